// Round 1
// baseline (306.685 us; speedup 1.0000x reference)
//
#include <hip/hip_runtime.h>

#define NC 5
#define VEC 4

__global__ __launch_bounds__(256) void flow_cpab_kernel(
    const float* __restrict__ x, const float* __restrict__ theta,
    const float* __restrict__ B, float* __restrict__ out, int n)
{
    __shared__ float s_a[NC], s_b[NC], s_bosa[NC], s_isa[NC], s_isb[NC];
    __shared__ int s_big[NC];

    const int tid = threadIdx.x;
    if (tid < NC) {
        // A = (B @ theta).reshape(nc,2); row 2*tid -> a, row 2*tid+1 -> b
        float a = 0.f, b = 0.f;
        #pragma unroll
        for (int j = 0; j < 6; ++j) {
            float th = theta[j];
            a = fmaf(B[(2 * tid) * 6 + j], th, a);
            b = fmaf(B[(2 * tid + 1) * 6 + j], th, b);
        }
        const bool big = fabsf(a) > 1e-8f;
        const float sa = big ? a : 1.0f;
        const float sb = (fabsf(b) > 1e-12f) ? b : 1e-12f;
        s_a[tid]    = a;
        s_b[tid]    = b;
        s_bosa[tid] = b / sa;      // full-precision, once per cell
        s_isa[tid]  = 1.0f / sa;
        s_isb[tid]  = 1.0f / sb;
        s_big[tid]  = big ? 1 : 0;
    }
    __syncthreads();

    const float EPS  = 1e-7f;
    const float TINY = 1e-12f;
    const float BIG  = 1e10f;
    const float inv_nc = 1.0f / (float)NC;

    const long long base = ((long long)blockIdx.x * blockDim.x + tid) * VEC;
    if (base >= n) return;

    float xs[VEC], zz[VEC], ll[VEC];
    const bool full = (base + VEC <= n);
    if (full) {
        float4 xv = *(const float4*)(x + base);
        xs[0] = xv.x; xs[1] = xv.y; xs[2] = xv.z; xs[3] = xv.w;
    } else {
        for (int p = 0; p < VEC; ++p)
            xs[p] = (base + p < n) ? x[base + p] : 0.5f;
    }

    #pragma unroll
    for (int p = 0; p < VEC; ++p) {
        float xc = fminf(fmaxf(xs[p], EPS), 1.0f - EPS);
        int c = (int)(xc * (float)NC);          // xc > 0 so trunc == floor
        c = min(max(c, 0), NC - 1);
        float t = 1.0f;
        float logder = 0.0f;

        #pragma unroll
        for (int it = 0; it < NC + 2; ++it) {
            const float a    = s_a[c];
            const float b    = s_b[c];
            const float bosa = s_bosa[c];
            const float isa  = s_isa[c];
            const float isb  = s_isb[c];
            const bool  big  = (s_big[c] != 0);

            const float v   = fmaf(a, xc, b);
            const float eat = __expf(a * t);
            const float psi = big ? fmaf(xc, eat, bosa * (eat - 1.0f))
                                  : fmaf(b, t, xc);
            const bool  right = (v >= 0.0f);
            const int   cb    = right ? (c + 1) : c;
            const float xb    = (float)cb * inv_nc;

            const float den   = xc + bosa;
            const float sden  = (fabsf(den) > TINY) ? den : TINY;
            const float ratio = __fdividef(xb + bosa, sden);
            const float thit_a = __logf(fmaxf(ratio, TINY)) * isa;
            const float thit_b = (xb - xc) * isb;
            float thit = big ? thit_a : thit_b;

            const bool valid = (fabsf(v) > TINY) && (thit >= 0.0f) &&
                               (!big || (ratio > 0.0f));
            thit = valid ? thit : BIG;

            const bool  hits = (thit < t);
            const float dt   = hits ? thit : t;
            xc = hits ? xb : psi;
            int cn = c + (right ? 1 : -1);
            cn = min(max(cn, 0), NC - 1);
            c  = hits ? cn : c;
            t -= dt;
            logder = fmaf(a, dt, logder);
        }
        zz[p] = xc;
        ll[p] = logder;
    }

    if (full) {
        *(float4*)(out + base)     = make_float4(zz[0], zz[1], zz[2], zz[3]);
        *(float4*)(out + n + base) = make_float4(ll[0], ll[1], ll[2], ll[3]);
    } else {
        for (int p = 0; p < VEC; ++p) {
            if (base + p < n) {
                out[base + p]     = zz[p];
                out[n + base + p] = ll[p];
            }
        }
    }
}

extern "C" void kernel_launch(void* const* d_in, const int* in_sizes, int n_in,
                              void* d_out, int out_size, void* d_ws, size_t ws_size,
                              hipStream_t stream) {
    const float* x     = (const float*)d_in[0];
    const float* theta = (const float*)d_in[1];
    const float* B     = (const float*)d_in[2];
    float* out = (float*)d_out;
    const int n = in_sizes[0];

    const int threads = 256;
    const int per_block = threads * VEC;
    const int blocks = (n + per_block - 1) / per_block;
    flow_cpab_kernel<<<blocks, threads, 0, stream>>>(x, theta, B, out, n);
}

// Round 2
// 291.314 us; speedup vs baseline: 1.0528x; 1.0528x over previous
//
#include <hip/hip_runtime.h>

#define NC 5
#define VEC 4

__global__ __launch_bounds__(256) void flow_cpab_kernel(
    const float* __restrict__ x, const float* __restrict__ theta,
    const float* __restrict__ B, float* __restrict__ out, int n)
{
    // Per-cell constants packed as two float4s -> 2x ds_read_b128 per iter.
    // k0 = {a, b, bosa, isa};  k1 = {isb, nR, nL, xbR}
    __shared__ float4 s_k0[NC], s_k1[NC];

    const int tid = threadIdx.x;
    if (tid < NC) {
        float a = 0.f, b = 0.f;
        #pragma unroll
        for (int j = 0; j < 6; ++j) {
            float th = theta[j];
            a = fmaf(B[(2 * tid) * 6 + j], th, a);
            b = fmaf(B[(2 * tid + 1) * 6 + j], th, b);
        }
        const bool  big = fabsf(a) > 1e-8f;
        const float sa  = big ? a : 1.0f;
        const float sb  = (fabsf(b) > 1e-12f) ? b : 1e-12f;
        const float bosa = b / sa;
        const float xbR  = (float)(tid + 1) / (float)NC;
        const float xbL  = (float)tid / (float)NC;
        s_k0[tid] = make_float4(a, b, bosa, 1.0f / sa);
        s_k1[tid] = make_float4(1.0f / sb, xbR + bosa, xbL + bosa, xbR);
    }
    __syncthreads();

    const float EPS  = 1e-7f;
    const float TINY = 1e-12f;
    const float BIG  = 1e10f;

    const int base = (blockIdx.x * blockDim.x + tid) * VEC;
    if (base >= n) return;

    float xs[VEC], zz[VEC], ll[VEC];
    const bool full = (base + VEC <= n);
    if (full) {
        float4 xv = *(const float4*)(x + base);
        xs[0] = xv.x; xs[1] = xv.y; xs[2] = xv.z; xs[3] = xv.w;
    } else {
        for (int p = 0; p < VEC; ++p)
            xs[p] = (base + p < n) ? x[base + p] : 0.5f;
    }

    #pragma unroll
    for (int p = 0; p < VEC; ++p) {
        float xc = fminf(fmaxf(xs[p], EPS), 1.0f - EPS);
        int c = min((int)(xc * (float)NC), NC - 1);   // xc > 0: trunc == floor
        float t = 1.0f;
        float logder = 0.0f;

        for (int it = 0; it < NC + 2; ++it) {
            const float4 k0 = s_k0[c];
            const float4 k1 = s_k1[c];
            const float a = k0.x, b = k0.y, bosa = k0.z, isa = k0.w;
            const float isb = k1.x, nR = k1.y, nL = k1.z, xbR = k1.w;

            const float v   = fmaf(a, xc, b);
            const bool  big = fabsf(a) > 1e-8f;
            const float eat = __expf(a * t);
            const float psi = big ? fmaf(xc, eat, bosa * (eat - 1.0f))
                                  : fmaf(b, t, xc);
            const bool  right = (v >= 0.0f);
            const float xb    = right ? xbR : (xbR - 1.0f / (float)NC);
            const float numer = right ? nR : nL;

            const float den   = xc + bosa;
            const float sden  = (fabsf(den) > TINY) ? den : TINY;
            const float ratio = __fdividef(numer, sden);
            const float thit_a = __logf(fmaxf(ratio, TINY)) * isa;
            const float thit_b = (xb - xc) * isb;
            float thit = big ? thit_a : thit_b;

            const bool valid = (fabsf(v) > TINY) && (thit >= 0.0f) &&
                               (!big || (ratio > 0.0f));
            thit = valid ? thit : BIG;

            const bool  hits = (thit < t);
            const float dt   = hits ? thit : t;
            xc = hits ? xb : psi;
            int cn = c + (right ? 1 : -1);
            cn = min(max(cn, 0), NC - 1);
            c  = hits ? cn : c;
            t -= dt;
            logder = fmaf(a, dt, logder);

            // Non-hit iteration zeroes t; all later iterations are no-ops.
            if (t <= 0.0f) break;
        }
        zz[p] = xc;
        ll[p] = logder;
    }

    if (full) {
        *(float4*)(out + base)     = make_float4(zz[0], zz[1], zz[2], zz[3]);
        *(float4*)(out + n + base) = make_float4(ll[0], ll[1], ll[2], ll[3]);
    } else {
        for (int p = 0; p < VEC; ++p) {
            if (base + p < n) {
                out[base + p]     = zz[p];
                out[n + base + p] = ll[p];
            }
        }
    }
}

extern "C" void kernel_launch(void* const* d_in, const int* in_sizes, int n_in,
                              void* d_out, int out_size, void* d_ws, size_t ws_size,
                              hipStream_t stream) {
    const float* x     = (const float*)d_in[0];
    const float* theta = (const float*)d_in[1];
    const float* B     = (const float*)d_in[2];
    float* out = (float*)d_out;
    const int n = in_sizes[0];

    const int threads = 256;
    const int per_block = threads * VEC;
    const int blocks = (n + per_block - 1) / per_block;
    flow_cpab_kernel<<<blocks, threads, 0, stream>>>(x, theta, B, out, n);
}

// Round 3
// 187.696 us; speedup vs baseline: 1.6339x; 1.5521x over previous
//
#include <hip/hip_runtime.h>

#define NC 5
#define VEC 4

// ws float layout (560 floats = 2240 B):
// [0..19]    k0[c] = {a, b, bosa, isa}          (c = 0..4)
// [20..24]   isb[c]
// [25..30]   bnd[j] = j/5.0f                    (j = 0..5)
// [32..79]   thr[d*6+jb] = float4 cumulative crossing-time thresholds
// [80..319]  pkgA[(d*6+jb)*5+m] = {Ccum, Lcum, x_entry, a_f}
// [320..559] pkgB[(d*6+jb)*5+m] = {b_f, bosa_f, 0, 0}

__global__ void setup_kernel(const float* __restrict__ theta,
                             const float* __restrict__ B,
                             float* __restrict__ ws)
{
    const int tid = threadIdx.x;
    const float TINY = 1e-12f, BIG = 1e10f;

    float a[NC], b[NC], bosa[NC], isa[NC], isbv[NC];
    #pragma unroll
    for (int c = 0; c < NC; ++c) {
        float av = 0.f, bv = 0.f;
        #pragma unroll
        for (int j = 0; j < 6; ++j) {
            float th = theta[j];
            av = fmaf(B[(2 * c) * 6 + j], th, av);
            bv = fmaf(B[(2 * c + 1) * 6 + j], th, bv);
        }
        const bool  big = fabsf(av) > 1e-8f;
        const float sa  = big ? av : 1.0f;
        const float sb  = (fabsf(bv) > TINY) ? bv : TINY;
        a[c] = av; b[c] = bv;
        bosa[c] = bv / sa;
        isa[c]  = 1.0f / sa;
        isbv[c] = 1.0f / sb;
    }

    if (tid < NC) {
        ws[tid * 4 + 0] = a[tid];
        ws[tid * 4 + 1] = b[tid];
        ws[tid * 4 + 2] = bosa[tid];
        ws[tid * 4 + 3] = isa[tid];
        ws[20 + tid]    = isbv[tid];
    }
    if (tid < 6) ws[25 + tid] = (float)tid / 5.0f;

    if (tid < 12) {
        const int d  = tid / 6;   // 0 = right, 1 = left
        const int jb = tid % 6;   // entry boundary index
        float Ccum = 0.f, Lcum = 0.f;
        float th0 = BIG, th1 = BIG, th2 = BIG, th3 = BIG;

        for (int m = 0; m < 5; ++m) {
            const int  cf   = (d == 0) ? (jb + m) : (jb - 1 - m);
            const bool sent = (cf < 0) || (cf >= NC);
            const float xe  = (d == 0) ? ((float)cf / 5.0f)
                                       : ((float)(cf + 1) / 5.0f);
            const float af    = sent ? 0.f : a[cf];
            const float bf    = sent ? 0.f : b[cf];
            const float bosaf = sent ? 0.f : bosa[cf];

            const int pix = tid * 5 + m;
            ws[ 80 + pix * 4 + 0] = Ccum;
            ws[ 80 + pix * 4 + 1] = Lcum;
            ws[ 80 + pix * 4 + 2] = xe;
            ws[ 80 + pix * 4 + 3] = af;
            ws[320 + pix * 4 + 0] = bf;
            ws[320 + pix * 4 + 1] = bosaf;
            ws[320 + pix * 4 + 2] = 0.f;
            ws[320 + pix * 4 + 3] = 0.f;

            float T = BIG;
            if (!sent) {
                const float xL  = (float)cf / 5.0f;
                const float xR  = (float)(cf + 1) / 5.0f;
                const float xce = (d == 0) ? xL : xR;   // entry
                const float xbt = (d == 0) ? xR : xL;   // target boundary
                const float v   = fmaf(af, xce, bf);
                const bool  big = fabsf(af) > 1e-8f;
                const float den  = xce + bosaf;
                const float sden = (fabsf(den) > TINY) ? den : TINY;
                const float ratio = __fdividef(xbt + bosaf, sden);
                const float ta = __logf(fmaxf(ratio, TINY)) * isa[cf];
                const float tb = (xbt - xce) * isbv[cf];
                float thit = big ? ta : tb;
                const bool valid = (fabsf(v) > TINY) && (thit >= 0.f) &&
                                   (!big || (ratio > 0.f));
                T = valid ? thit : BIG;
            }
            const float newC = Ccum + T;
            if (m == 0) th0 = newC;
            if (m == 1) th1 = newC;
            if (m == 2) th2 = newC;
            if (m == 3) th3 = newC;
            if (T < BIG) Lcum = fmaf(af, T, Lcum);
            Ccum = newC;
        }
        ws[32 + tid * 4 + 0] = th0;
        ws[32 + tid * 4 + 1] = th1;
        ws[32 + tid * 4 + 2] = th2;
        ws[32 + tid * 4 + 3] = th3;
    }
}

__global__ __launch_bounds__(256) void flow_cpab_kernel(
    const float* __restrict__ x, const float* __restrict__ ws,
    float* __restrict__ out, int n)
{
    __shared__ float s[560];
    const int tid = threadIdx.x;
    if (tid < 140) ((float4*)s)[tid] = ((const float4*)ws)[tid];
    __syncthreads();

    const float4* s_k0   = (const float4*)(s);         // [5]
    const float*  s_isb  = s + 20;                     // [5]
    const float*  s_bnd  = s + 25;                     // [6]
    const float4* s_thr  = (const float4*)(s + 32);    // [12]
    const float4* s_pA   = (const float4*)(s + 80);    // [60]
    const float4* s_pB   = (const float4*)(s + 320);   // [60]

    const float EPS  = 1e-7f;
    const float TINY = 1e-12f;
    const float BIG  = 1e10f;

    const int base = (blockIdx.x * blockDim.x + tid) * VEC;
    if (base >= n) return;

    float xs[VEC], zz[VEC], ll[VEC];
    const bool full = (base + VEC <= n);
    if (full) {
        float4 xv = *(const float4*)(x + base);
        xs[0] = xv.x; xs[1] = xv.y; xs[2] = xv.z; xs[3] = xv.w;
    } else {
        for (int p = 0; p < VEC; ++p)
            xs[p] = (base + p < n) ? x[base + p] : 0.5f;
    }

    #pragma unroll
    for (int p = 0; p < VEC; ++p) {
        const float xc = fminf(fmaxf(xs[p], EPS), 1.0f - EPS);
        const int c0 = min((int)(xc * (float)NC), NC - 1);

        const float4 k0 = s_k0[c0];
        const float a = k0.x, b = k0.y, bosa = k0.z, isa = k0.w;
        const float isb = s_isb[c0];
        const bool  big = fabsf(a) > 1e-8f;

        // ---- first leg: x -> nearest boundary in flow direction ----
        const float v     = fmaf(a, xc, b);
        const bool  right = (v >= 0.0f);
        const int   cb    = c0 + (right ? 1 : 0);
        const float xb    = s_bnd[cb];

        const float den   = xc + bosa;
        const float sden  = (fabsf(den) > TINY) ? den : TINY;
        const float ratio = __fdividef(xb + bosa, sden);
        const float th_a  = __logf(fmaxf(ratio, TINY)) * isa;
        const float th_b  = (xb - xc) * isb;
        float thit0 = big ? th_a : th_b;
        const bool valid = (fabsf(v) > TINY) && (thit0 >= 0.0f) &&
                           (!big || (ratio > 0.0f));
        thit0 = valid ? thit0 : BIG;

        const bool  hit0 = (thit0 < 1.0f);
        const float tr   = 1.0f - thit0;

        // ---- full-cell scan via precomputed cumulative thresholds ----
        const int tix = (right ? 0 : 6) + cb;     // jb == cb in both dirs
        const float4 th = s_thr[tix];
        const int m = (th.x < tr) + (th.y < tr) + (th.z < tr) + (th.w < tr);
        const int pix = tix * 5 + m;
        const float4 pA = s_pA[pix];
        const float4 pB = s_pB[pix];

        // ---- final partial-cell evolution ----
        const float xe    = hit0 ? pA.z : xc;
        const float t_f   = hit0 ? (tr - pA.x) : 1.0f;
        const float af    = hit0 ? pA.w : a;
        const float bf    = hit0 ? pB.x : b;
        const float bosaf = hit0 ? pB.y : bosa;
        const float lbase = hit0 ? fmaf(a, thit0, pA.y) : 0.0f;

        const bool  bigf = fabsf(af) > 1e-8f;
        const float eat  = __expf(af * t_f);
        zz[p] = bigf ? fmaf(xe, eat, bosaf * (eat - 1.0f))
                     : fmaf(bf, t_f, xe);
        ll[p] = fmaf(af, t_f, lbase);
    }

    if (full) {
        *(float4*)(out + base)     = make_float4(zz[0], zz[1], zz[2], zz[3]);
        *(float4*)(out + n + base) = make_float4(ll[0], ll[1], ll[2], ll[3]);
    } else {
        for (int p = 0; p < VEC; ++p) {
            if (base + p < n) {
                out[base + p]     = zz[p];
                out[n + base + p] = ll[p];
            }
        }
    }
}

extern "C" void kernel_launch(void* const* d_in, const int* in_sizes, int n_in,
                              void* d_out, int out_size, void* d_ws, size_t ws_size,
                              hipStream_t stream) {
    const float* x     = (const float*)d_in[0];
    const float* theta = (const float*)d_in[1];
    const float* B     = (const float*)d_in[2];
    float* out = (float*)d_out;
    float* ws  = (float*)d_ws;
    const int n = in_sizes[0];

    setup_kernel<<<1, 64, 0, stream>>>(theta, B, ws);

    const int threads = 256;
    const int per_block = threads * VEC;
    const int blocks = (n + per_block - 1) / per_block;
    flow_cpab_kernel<<<blocks, threads, 0, stream>>>(x, ws, out, n);
}